// Round 9
// baseline (9743.903 us; speedup 1.0000x reference)
//
#include <hip/hip_runtime.h>

typedef _Float16 half8 __attribute__((ext_vector_type(8)));
typedef float    f32x4 __attribute__((ext_vector_type(4)));
typedef int      int4v __attribute__((ext_vector_type(4)));

#define TT 512
#define BB 256
#define INDIM 8
#define HH 512

// ---- workspace layout ----
// floats [0, 131072)             : h1 final fp32 (head input)
// halves b16 = ws+131072 floats  : h0h[2] (2x131072), h1h[2] (2x131072),
//                                  Wpk [32 jg][144 nl][512 k] (logical layout)
// bytes 6291456                  : flags, 4 groups x 32 ints (one 128B line each)

__global__ void prep_kernel(const float* __restrict__ Whh0,
                            const float* __restrict__ Wih1,
                            const float* __restrict__ Whh1,
                            float* __restrict__ ws)
{
    const int NW = 32*144*512;                 // 2359296 packed weight halves
    _Float16* b16 = (_Float16*)(ws + 131072);
    _Float16* Wpk = b16 + 524288;
    int* flags = (int*)((char*)ws + 6291456);
    long long idx = (long long)blockIdx.x*256 + threadIdx.x;
    if (idx < NW) {
        int e   = (int)idx;
        int jg  = e / (144*512);
        int rem = e % (144*512);
        int nl  = rem >> 9;                    // 0..143 = g9*16 + m
        int k   = rem & 511;                   // logical k
        int g9  = nl >> 4;
        int m   = nl & 15;
        int j   = jg*16 + m;
        float v;
        if      (g9 < 3) v = Whh0[(size_t)(g9*HH + j)*HH + k];
        else if (g9 < 6) v = Wih1[(size_t)((g9-3)*HH + j)*HH + k];
        else             v = Whh1[(size_t)((g9-6)*HH + j)*HH + k];
        Wpk[e] = (_Float16)v;
    } else if (idx < NW + 524288) {
        b16[idx - NW] = (_Float16)0.0f;        // zero all 4 f16 h buffers
    } else if (idx < NW + 524288 + 256) {
        flags[idx - NW - 524288] = 0;          // zero flag slots
    } else if (idx < NW + 524288 + 256 + 131072) {
        ws[idx - (NW + 524288 + 256)] = 1.0e-3f;  // sentinel canary
    }
}

// 128 blocks x 256 threads (4 waves), PLAIN launch.
// bg = blk&3 (batch group of 64), jg = blk>>2 (j-slice of 16).
// Cross-XCD h exchange via sc0+sc1 (LLC-coherent) loads/stores — no fences,
// no RMW. Flags: per-block slot store (sc1); ALL waves poll the 128B line
// with 8 parallel dwordx4 sc1 loads (LLC-coherent detection — R8's volatile
// polls spun on stale local L2 and detection waited for capacity eviction).
__global__ void __launch_bounds__(256, 1)
gru_main(const float* __restrict__ x,
         const float* __restrict__ Wih0, const float* __restrict__ bih0,
         const float* __restrict__ bhh0, const float* __restrict__ bih1,
         const float* __restrict__ bhh1, float* __restrict__ ws)
{
    __shared__ __align__(16) _Float16 WlL[144*192];   // 55296 B

    const int tid = threadIdx.x;
    const int blk = blockIdx.x;        // 0..127
    const int bg  = blk & 3;
    const int jg  = blk >> 2;          // 0..31

    float* h1f = ws;
    _Float16* b16 = (_Float16*)(ws + 131072);
    _Float16* h0h[2] = { b16,          b16 + 131072 };
    _Float16* h1h[2] = { b16 + 262144, b16 + 393216 };
    const _Float16* Wpk = b16 + 524288;
    int* grpflags = (int*)((char*)ws + 6291456) + bg*32;  // 128B line
    int* myslot   = grpflags + jg;

    const _Float16* WpkB = Wpk + (size_t)jg*(144*512);

    // ---- one-time LDS fill: k-steps 0..5, XOR-swizzled granules ----
    for (int t = tid; t < 144*24; t += 256) {
        int nl = t / 24, gg = t % 24;
        int slot = gg ^ ((nl >> 1) & 7);
        *(float4*)&WlL[nl*192 + slot*8] = *(const float4*)&WpkB[(size_t)nl*512 + gg*8];
    }
    __syncthreads();

    const int lane = tid & 63;
    const int wv   = tid >> 6;          // wave 0..3 = batch tile
    const int m    = lane & 15;         // j-local / A,B frag row
    const int q    = lane >> 4;         // 0..3
    const int key  = (m >> 1) & 7;      // LDS swizzle key (matches fill)
    const int j    = jg*16 + m;
    const int bb   = bg*64 + wv*16;     // wave's batch base

    // ---- per-lane constants ----
    float w0[3][8];
    #pragma unroll
    for (int g = 0; g < 3; ++g)
        #pragma unroll
        for (int kk = 0; kk < 8; ++kk)
            w0[g][kk] = Wih0[(size_t)(g*HH + j)*INDIM + kk];
    const float br0  = bih0[j]      + bhh0[j];
    const float bz0  = bih0[HH+j]   + bhh0[HH+j];
    const float bni0 = bih0[2*HH+j];
    const float bnh0 = bhh0[2*HH+j];
    const float br1  = bih1[j]      + bhh1[j];
    const float bz1  = bih1[HH+j]   + bhh1[HH+j];
    const float bni1 = bih1[2*HH+j];
    const float bnh1 = bhh1[2*HH+j];

    // ---- VGPR B-cache: k-steps 6..7 ----
    half8 Bc[2][9];
    #pragma unroll
    for (int s = 0; s < 2; ++s)
        #pragma unroll
        for (int g = 0; g < 9; ++g)
            Bc[s][g] = *(const half8*)&WpkB[(size_t)(g*16+m)*512 + (6+s)*32 + q*8];

    // fp32 hidden state carried in registers (lane owns rows q*4+r, col j)
    float h0pr[4] = {0.f,0.f,0.f,0.f};
    float h1pr[4] = {0.f,0.f,0.f,0.f};

    for (int p = 0; p <= TT; ++p) {
        const _Float16* h0p = h0h[(p+1)&1];   // h0[p-1]
        const _Float16* h1p = h1h[p&1];       // h1[p-2]
        const _Float16* a0base = h0p + (size_t)(bb + m)*HH + q*8;
        const _Float16* a1base = h1p + (size_t)(bb + m)*HH + q*8;

        // ---- A fragments: 32 LLC-coherent loads in flight, one waitcnt ----
        half8 a0s[16], a1s[16];
        #pragma unroll
        for (int s = 0; s < 16; ++s) {
            asm volatile("global_load_dwordx4 %0, %1, off sc0 sc1"
                         : "=v"(a0s[s]) : "v"(a0base + s*32));
            asm volatile("global_load_dwordx4 %0, %1, off sc0 sc1"
                         : "=v"(a1s[s]) : "v"(a1base + s*32));
        }
        asm volatile("s_waitcnt vmcnt(0)"
            : "+v"(a0s[0]),"+v"(a0s[1]),"+v"(a0s[2]),"+v"(a0s[3]),
              "+v"(a0s[4]),"+v"(a0s[5]),"+v"(a0s[6]),"+v"(a0s[7]),
              "+v"(a0s[8]),"+v"(a0s[9]),"+v"(a0s[10]),"+v"(a0s[11]),
              "+v"(a0s[12]),"+v"(a0s[13]),"+v"(a0s[14]),"+v"(a0s[15]));
        asm volatile(""
            : "+v"(a1s[0]),"+v"(a1s[1]),"+v"(a1s[2]),"+v"(a1s[3]),
              "+v"(a1s[4]),"+v"(a1s[5]),"+v"(a1s[6]),"+v"(a1s[7]),
              "+v"(a1s[8]),"+v"(a1s[9]),"+v"(a1s[10]),"+v"(a1s[11]),
              "+v"(a1s[12]),"+v"(a1s[13]),"+v"(a1s[14]),"+v"(a1s[15]));

        f32x4 acc[9];
        #pragma unroll
        for (int g = 0; g < 9; ++g) acc[g] = (f32x4){0.f,0.f,0.f,0.f};

        // ---- steps 0..5: B from LDS ----
        #pragma unroll
        for (int s = 0; s < 6; ++s) {
            #pragma unroll
            for (int g = 0; g < 9; ++g) {
                half8 bf = *(const half8*)&WlL[(g*16+m)*192 + (((s*4+q) ^ key))*8];
                acc[g] = __builtin_amdgcn_mfma_f32_16x16x32_f16((g < 6) ? a0s[s] : a1s[s], bf, acc[g], 0, 0, 0);
            }
        }
        // ---- steps 6..7: B from VGPR cache ----
        #pragma unroll
        for (int s = 0; s < 2; ++s) {
            #pragma unroll
            for (int g = 0; g < 9; ++g)
                acc[g] = __builtin_amdgcn_mfma_f32_16x16x32_f16((g < 6) ? a0s[6+s] : a1s[6+s], Bc[s][g], acc[g], 0, 0, 0);
        }
        // ---- steps 8..15: B pipelined one step ahead from (warm) L2 ----
        half8 nb[9];
        #pragma unroll
        for (int g = 0; g < 9; ++g)
            nb[g] = *(const half8*)&WpkB[(size_t)(g*16+m)*512 + 8*32 + q*8];
        #pragma unroll
        for (int s = 8; s < 16; ++s) {
            half8 cb[9];
            #pragma unroll
            for (int g = 0; g < 9; ++g) cb[g] = nb[g];
            if (s < 15) {
                #pragma unroll
                for (int g = 0; g < 9; ++g)
                    nb[g] = *(const half8*)&WpkB[(size_t)(g*16+m)*512 + (s+1)*32 + q*8];
            }
            #pragma unroll
            for (int g = 0; g < 9; ++g)
                acc[g] = __builtin_amdgcn_mfma_f32_16x16x32_f16((g < 6) ? a0s[s] : a1s[s], cb[g], acc[g], 0, 0, 0);
        }

        // ---- fused epilogues: h stores are sc0+sc1 write-through to LLC ----
        _Float16* h0n = h0h[p&1];
        _Float16* h1n = h1h[(p+1)&1];
        if (p < TT) {
            #pragma unroll
            for (int r = 0; r < 4; ++r) {
                const int b = bb + q*4 + r;
                const float* xv = x + ((size_t)p*BB + b)*INDIM;
                float4 xa = *(const float4*)xv;
                float4 xb = *(const float4*)(xv + 4);
                float gr = xa.x*w0[0][0]+xa.y*w0[0][1]+xa.z*w0[0][2]+xa.w*w0[0][3]
                         + xb.x*w0[0][4]+xb.y*w0[0][5]+xb.z*w0[0][6]+xb.w*w0[0][7];
                float gz = xa.x*w0[1][0]+xa.y*w0[1][1]+xa.z*w0[1][2]+xa.w*w0[1][3]
                         + xb.x*w0[1][4]+xb.y*w0[1][5]+xb.z*w0[1][6]+xb.w*w0[1][7];
                float gn = xa.x*w0[2][0]+xa.y*w0[2][1]+xa.z*w0[2][2]+xa.w*w0[2][3]
                         + xb.x*w0[2][4]+xb.y*w0[2][5]+xb.z*w0[2][6]+xb.w*w0[2][7];
                float rg = 1.f/(1.f + __expf(-(gr + acc[0][r] + br0)));
                float zg = 1.f/(1.f + __expf(-(gz + acc[1][r] + bz0)));
                float ng = tanhf(gn + bni0 + rg*(acc[2][r] + bnh0));
                float hv = (1.f - zg)*ng + zg*h0pr[r];
                h0pr[r] = hv;
                _Float16 hv16 = (_Float16)hv;
                asm volatile("global_store_short %0, %1, off sc0 sc1"
                             :: "v"(h0n + (size_t)b*HH + j), "v"(hv16) : "memory");
            }
        }
        if (p >= 1) {
            #pragma unroll
            for (int r = 0; r < 4; ++r) {
                const int b = bb + q*4 + r;
                float rg = 1.f/(1.f + __expf(-(acc[3][r] + acc[6][r] + br1)));
                float zg = 1.f/(1.f + __expf(-(acc[4][r] + acc[7][r] + bz1)));
                float ng = tanhf(acc[5][r] + bni1 + rg*(acc[8][r] + bnh1));
                float hv = (1.f - zg)*ng + zg*h1pr[r];
                h1pr[r] = hv;
                _Float16 hv16 = (_Float16)hv;
                asm volatile("global_store_short %0, %1, off sc0 sc1"
                             :: "v"(h1n + (size_t)b*HH + j), "v"(hv16) : "memory");
                if (p == TT) h1f[(size_t)b*HH + j] = hv;   // kernel-boundary flush
            }
        }

        // ---- rendezvous: drain -> block arrival -> sc1 slot store ->
        //      all-wave LLC-coherent parallel poll (no trailing barrier) ----
        if (p < TT) {
            asm volatile("s_waitcnt vmcnt(0)" ::: "memory");
            __syncthreads();                       // all 4 waves' stores at LLC
            if (tid == 0) {
                int pv = p + 1;
                asm volatile("global_store_dword %0, %1, off sc0 sc1"
                             :: "v"(myslot), "v"(pv) : "memory");
            }
            // lanes 0..7 each load 4 slots (one 128B line, 8 loads in flight)
            while (true) {
                bool ok = true;
                if (lane < 8) {
                    int4v fv;
                    asm volatile("global_load_dwordx4 %0, %1, off sc0 sc1"
                                 : "=v"(fv) : "v"(grpflags + lane*4));
                    asm volatile("s_waitcnt vmcnt(0)" : "+v"(fv));
                    ok = (fv.x > p) & (fv.y > p) & (fv.z > p) & (fv.w > p);
                }
                if (__all(ok)) break;
                __builtin_amdgcn_s_sleep(1);
            }
        }
    }
}

__global__ void head_kernel(const float* __restrict__ ws,
                            const float* __restrict__ Wout,
                            const float* __restrict__ bout,
                            float* __restrict__ out)
{
    const float* h1 = ws;               // h1[511] fp32
    int b = blockIdx.x;
    int lane = threadIdx.x;             // 64
    for (int o = 0; o < 5; ++o) {
        float s = 0.f;
        for (int k = lane; k < HH; k += 64)
            s += h1[(size_t)b*HH + k] * Wout[(size_t)o*HH + k];
        for (int off = 32; off > 0; off >>= 1)
            s += __shfl_xor(s, off, 64);
        if (lane == 0) out[b*5 + o] = s + bout[o];
    }
}

extern "C" void kernel_launch(void* const* d_in, const int* in_sizes, int n_in,
                              void* d_out, int out_size, void* d_ws, size_t ws_size,
                              hipStream_t stream) {
    const float* x    = (const float*)d_in[0];
    const float* Wih0 = (const float*)d_in[1];
    const float* Whh0 = (const float*)d_in[2];
    const float* bih0 = (const float*)d_in[3];
    const float* bhh0 = (const float*)d_in[4];
    const float* Wih1 = (const float*)d_in[5];
    const float* Whh1 = (const float*)d_in[6];
    const float* bih1 = (const float*)d_in[7];
    const float* bhh1 = (const float*)d_in[8];
    const float* Wout = (const float*)d_in[9];
    const float* bout = (const float*)d_in[10];
    float* out = (float*)d_out;
    float* ws  = (float*)d_ws;   // needs ~6.3 MB

    // 1) pack weights to f16 + zero f16 state + zero flags + sentinel h1f
    const long long total = 32LL*144*512 + 524288 + 256 + 131072;
    int pblocks = (int)((total + 255) / 256);
    hipLaunchKernelGGL(prep_kernel, dim3(pblocks), dim3(256), 0, stream,
                       Whh0, Wih1, Whh1, ws);

    // 2) persistent recurrence — plain launch, 128 blocks x 256 thr,
    //    1 block/CU, all co-resident.
    hipLaunchKernelGGL(gru_main, dim3(128), dim3(256), 0, stream,
                       x, Wih0, bih0, bhh0, bih1, bhh1, ws);

    // 3) linear head
    hipLaunchKernelGGL(head_kernel, dim3(256), dim3(64), 0, stream,
                       (const float*)ws, Wout, bout, out);
}